// Round 3
// baseline (424.114 us; speedup 1.0000x reference)
//
#include <hip/hip_runtime.h>
#include <hip/hip_bf16.h>

#define B_ 16
#define S_ 4096
#define C_ 320
#define KK_ 77
#define D_ 768
#define H_ 8
#define DH_ 40
#define KP_ 80           // padded keys per head
#define NP_ (H_ * KP_)   // 640
#define TAU_ 0.1f
#define GAMMA_ 1.0f
#define EPS_ 1e-12f

typedef __bf16 bf16x8 __attribute__((ext_vector_type(8)));
typedef float f32x4 __attribute__((ext_vector_type(4)));

__device__ __forceinline__ unsigned short f2bf(float f) {
    union { float f; unsigned u; } v; v.f = f;
    unsigned r = v.u + 0x7fffu + ((v.u >> 16) & 1u);
    return (unsigned short)(r >> 16);
}

// ---------------------------------------------------------------- build_M
// Bmat[n][Dk] bf16, n = which*2560 + h*320 + c:
//   which=0: scale * sum_d Wk[Dk, h*40+d] * Wq[c, h*40+d]
//   which=1:         sum_d Wv[Dk, h*40+d] * Wo[h*40+d, c]
__global__ __launch_bounds__(256) void build_M(const float* __restrict__ Wq,
        const float* __restrict__ Wk, const float* __restrict__ Wv,
        const float* __restrict__ Wo, unsigned short* __restrict__ Bmat) {
    const int Dk = blockIdx.x * 256 + threadIdx.x;     // 0..767
    const int h = blockIdx.y;
    const int which = blockIdx.z >> 2;
    const int c0 = (blockIdx.z & 3) * 80;
    __shared__ float wlds[80 * 44];                    // float4-readable
    for (int i = threadIdx.x; i < 80 * DH_; i += 256) {
        int c = i / DH_, d = i % DH_;
        wlds[c * 44 + d] = which
            ? Wo[(size_t)(h * DH_ + d) * C_ + (c0 + c)]
            : Wq[(size_t)(c0 + c) * C_ + h * DH_ + d];
    }
    float a[DH_];
    const float* Arow = (which ? Wv : Wk) + (size_t)Dk * C_ + h * DH_;
    #pragma unroll
    for (int d = 0; d < DH_; ++d) a[d] = Arow[d];
    __syncthreads();
    const float scale = 0.15811388300841898f;          // 1/sqrt(40)
    for (int c = 0; c < 80; ++c) {
        float s = 0.f;
        #pragma unroll
        for (int q = 0; q < 10; ++q) {
            float4 wv4 = *(const float4*)&wlds[c * 44 + q * 4];
            s += a[q * 4 + 0] * wv4.x + a[q * 4 + 1] * wv4.y
               + a[q * 4 + 2] * wv4.z + a[q * 4 + 3] * wv4.w;
        }
        if (!which) s *= scale;
        int n = which * 2560 + h * C_ + c0 + c;
        Bmat[(size_t)n * D_ + Dk] = f2bf(s);
    }
}

// ---------------------------------------------------------------- prep_ehs
// ehs f32 -> ehs_bf [16][80][768] bf16 (kk>=77 zero), + penalty (padded to 80)
// wave-per-row, no LDS
__global__ __launch_bounds__(256) void prep_ehs(const float* __restrict__ ehs,
        const float* __restrict__ harm, unsigned short* __restrict__ ehs_bf,
        float* __restrict__ pen) {
    const int w = threadIdx.x >> 6, l = threadIdx.x & 63;
    const int kk = blockIdx.x * 4 + w, b = blockIdx.y;
    const size_t obase = ((size_t)b * KP_ + kk) * D_;
    if (kk >= KK_) {
        #pragma unroll
        for (int j = 0; j < 12; ++j) ehs_bf[obase + l + j * 64] = 0;
        if (l == 0) pen[b * KP_ + kk] = 0.f;
        return;
    }
    const float* er = ehs + ((size_t)b * KK_ + kk) * D_;
    float ss = 0.f, dd = 0.f, hh = 0.f;
    #pragma unroll
    for (int j = 0; j < 12; ++j) {
        float e = er[l + j * 64], hv = harm[l + j * 64];
        ehs_bf[obase + l + j * 64] = f2bf(e);
        ss += e * e; dd += e * hv; hh += hv * hv;
    }
    #pragma unroll
    for (int off = 32; off; off >>= 1) {
        ss += __shfl_xor(ss, off);
        dd += __shfl_xor(dd, off);
        hh += __shfl_xor(hh, off);
    }
    if (l == 0) {
        float cs = dd / (fmaxf(sqrtf(ss), EPS_) * fmaxf(sqrtf(hh), EPS_));
        pen[b * KP_ + kk] = GAMMA_ * fmaxf(cs - TAU_, 0.f);
    }
}

// ---------------------------------------------------------------- gemm_WpU
// out[kk][n] = ehs_bf[b] @ Bmat^T ; n<2560 -> Wp[b][(h,kk)][c], else U[b][c'][(h,kk)]
// 2-deep software pipeline on global fragment loads.
__global__ __launch_bounds__(512) void gemm_WpU(
        const unsigned short* __restrict__ ehs_bf,
        const unsigned short* __restrict__ Bmat,
        unsigned short* __restrict__ Wp, unsigned short* __restrict__ U) {
    const int id = blockIdx.x;               // 640 = 8 xcd * (16 b * 5)
    const int xcd = id & 7, j = id >> 3;     // j 0..79
    const int b = j & 15, nt = xcd + 8 * (j >> 4);   // nt 0..39
    const int w = threadIdx.x >> 6, l = threadIdx.x & 63;
    const int lrow = l & 15, lk = (l >> 4) * 8;
    const int n = nt * 128 + w * 16;
    const unsigned short* Ar = ehs_bf + (size_t)b * KP_ * D_ + (size_t)lrow * D_ + lk;
    const unsigned short* Brow = Bmat + (size_t)(n + lrow) * D_ + lk;
    f32x4 acc[5];
    #pragma unroll
    for (int mf = 0; mf < 5; ++mf) acc[mf] = (f32x4){0.f, 0.f, 0.f, 0.f};
    bf16x8 aC[5], aN[5], bC, bN;
    bC = *(const bf16x8*)(Brow);
    #pragma unroll
    for (int mf = 0; mf < 5; ++mf) aC[mf] = *(const bf16x8*)(Ar + (size_t)mf * 16 * D_);
    #pragma unroll
    for (int ks = 0; ks < D_ / 32; ++ks) {
        if (ks < D_ / 32 - 1) {
            bN = *(const bf16x8*)(Brow + (ks + 1) * 32);
            #pragma unroll
            for (int mf = 0; mf < 5; ++mf)
                aN[mf] = *(const bf16x8*)(Ar + (size_t)mf * 16 * D_ + (ks + 1) * 32);
        }
        __builtin_amdgcn_s_setprio(1);
        #pragma unroll
        for (int mf = 0; mf < 5; ++mf)
            acc[mf] = __builtin_amdgcn_mfma_f32_16x16x32_bf16(aC[mf], bC, acc[mf], 0, 0, 0);
        __builtin_amdgcn_s_setprio(0);
        bC = bN;
        #pragma unroll
        for (int mf = 0; mf < 5; ++mf) aC[mf] = aN[mf];
    }
    const int col = n + lrow;
    if (col < 2560) {
        const int h = col / C_, c = col % C_;
        #pragma unroll
        for (int mf = 0; mf < 5; ++mf)
            #pragma unroll
            for (int r = 0; r < 4; ++r) {
                int kk = mf * 16 + (l >> 4) * 4 + r;
                Wp[((size_t)b * NP_ + h * KP_ + kk) * C_ + c] = f2bf(acc[mf][r]);
            }
    } else {
        const int n2 = col - 2560;
        const int h = n2 / C_, c = n2 % C_;
        #pragma unroll
        for (int mf = 0; mf < 5; ++mf)
            #pragma unroll
            for (int r = 0; r < 4; ++r) {
                int kk = mf * 16 + (l >> 4) * 4 + r;
                U[((size_t)b * C_ + c) * NP_ + h * KP_ + kk] = f2bf(acc[mf][r]);
            }
    }
}

// ---------------------------------------------------------------- fused attn
// 1024 threads (16 waves), 64 S-rows per block. phase1: 2 waves/head.
// LDS union 80 KB: hs tile (stride 328) then P (stride 640, XOR swizzle).
__global__ __launch_bounds__(1024, 4) void fused_attn(
        const float* __restrict__ hs, const unsigned short* __restrict__ Wp,
        const unsigned short* __restrict__ U, const float* __restrict__ pen,
        const float* __restrict__ bo, float* __restrict__ out) {
    const int id = blockIdx.x;                  // 1024 = 8 xcd * 128
    const int xcd = id & 7, rest = id >> 3;
    const int x = rest & 63;
    const int b = xcd * 2 + (rest >> 6);        // 2 batches per XCD
    const int s0 = x * 64;
    __shared__ unsigned short uni[64 * 640];    // 81920 B
    const int tid = threadIdx.x;
    const int w = tid >> 6, l = tid & 63;
    const int lrow = l & 15, lk = (l >> 4) * 8;

    // phase-1 role: 2 waves per head
    const int h = w & 7, mh = w >> 3;
    const unsigned short* WpB = Wp + ((size_t)b * NP_ + h * KP_) * C_;
    // phase-2 role
    const int mgrp = w & 3, ngrp = w >> 2;
    const unsigned short* UB = U + ((size_t)b * C_ + ngrp * 80) * NP_;

    // prefetch phase-1 B ks=0 + penalty (before staging barrier)
    bf16x8 bC[5], bN[5];
    #pragma unroll
    for (int nf = 0; nf < 5; ++nf)
        bC[nf] = *(const bf16x8*)(&WpB[(size_t)(nf * 16 + lrow) * C_ + lk]);
    float pv[5];
    #pragma unroll
    for (int nf = 0; nf < 5; ++nf) pv[nf] = pen[b * KP_ + nf * 16 + lrow];

    // stage hs tile (f32 -> bf16), stride 328
    const float4* hv = (const float4*)(hs + ((size_t)b * S_ + s0) * C_);
    #pragma unroll
    for (int it = 0; it < 5; ++it) {
        int i = tid + it * 1024;
        float4 v = hv[i];
        int e0 = i * 4, r = e0 / C_, c = e0 % C_;
        ushort4 u;
        u.x = f2bf(v.x); u.y = f2bf(v.y); u.z = f2bf(v.z); u.w = f2bf(v.w);
        *(ushort4*)(&uni[r * 328 + c]) = u;
    }
    __syncthreads();

    // ---- phase 1: scores, 2-deep pipelined
    f32x4 acc[2][5];
    #pragma unroll
    for (int mf = 0; mf < 2; ++mf)
        #pragma unroll
        for (int nf = 0; nf < 5; ++nf)
            acc[mf][nf] = (f32x4){0.f, 0.f, 0.f, 0.f};
    #pragma unroll
    for (int ks = 0; ks < C_ / 32; ++ks) {
        if (ks < C_ / 32 - 1) {
            #pragma unroll
            for (int nf = 0; nf < 5; ++nf)
                bN[nf] = *(const bf16x8*)(&WpB[(size_t)(nf * 16 + lrow) * C_ + (ks + 1) * 32 + lk]);
        }
        bf16x8 af[2];
        #pragma unroll
        for (int mf = 0; mf < 2; ++mf)
            af[mf] = *(const bf16x8*)(&uni[(mh * 32 + mf * 16 + lrow) * 328 + ks * 32 + lk]);
        __builtin_amdgcn_s_setprio(1);
        #pragma unroll
        for (int mf = 0; mf < 2; ++mf)
            #pragma unroll
            for (int nf = 0; nf < 5; ++nf)
                acc[mf][nf] = __builtin_amdgcn_mfma_f32_16x16x32_bf16(
                    af[mf], bC[nf], acc[mf][nf], 0, 0, 0);
        __builtin_amdgcn_s_setprio(0);
        #pragma unroll
        for (int nf = 0; nf < 5; ++nf) bC[nf] = bN[nf];
    }

    // prefetch phase-2 U ks=0 (latency hidden under softmax)
    bf16x8 uC[5], uN[5];
    #pragma unroll
    for (int nf = 0; nf < 5; ++nf)
        uC[nf] = *(const bf16x8*)(&UB[(size_t)(nf * 16 + lrow) * NP_ + lk]);

    // ---- softmax (8 rows per lane)
    #pragma unroll
    for (int mf = 0; mf < 2; ++mf) {
        #pragma unroll
        for (int r = 0; r < 4; ++r) {
            float v0[5]; float m = -1e30f;
            #pragma unroll
            for (int nf = 0; nf < 5; ++nf) {
                int kk = nf * 16 + lrow;
                float xv = acc[mf][nf][r] - pv[nf];
                v0[nf] = (kk < KK_) ? xv : -1e30f;
                m = fmaxf(m, v0[nf]);
            }
            #pragma unroll
            for (int off = 8; off; off >>= 1) m = fmaxf(m, __shfl_xor(m, off));
            float s = 0.f;
            #pragma unroll
            for (int nf = 0; nf < 5; ++nf) {
                float e = __expf(v0[nf] - m);
                v0[nf] = e; s += e;
            }
            #pragma unroll
            for (int off = 8; off; off >>= 1) s += __shfl_xor(s, off);
            float inv = 1.f / s;
            #pragma unroll
            for (int nf = 0; nf < 5; ++nf) acc[mf][nf][r] = v0[nf] * inv;
        }
    }
    __syncthreads();   // all waves done reading hs region

    // write P bf16, XOR swizzle (row*1280 + col*2) ^ ((row&7)<<4)
    {
        char* base = (char*)uni;
        #pragma unroll
        for (int mf = 0; mf < 2; ++mf)
            #pragma unroll
            for (int r = 0; r < 4; ++r) {
                int row = mh * 32 + mf * 16 + (l >> 4) * 4 + r;
                #pragma unroll
                for (int nf = 0; nf < 5; ++nf) {
                    int col = h * KP_ + nf * 16 + lrow;
                    int a = (row * 1280 + col * 2) ^ ((row & 7) << 4);
                    *(unsigned short*)(base + a) = f2bf(acc[mf][nf][r]);
                }
            }
    }
    __syncthreads();

    // ---- phase 2: out = P @ U + bo  (16 waves: 4 m x 4 n), 2-deep pipelined
    {
        f32x4 acc2[5];
        #pragma unroll
        for (int nf = 0; nf < 5; ++nf) acc2[nf] = (f32x4){0.f, 0.f, 0.f, 0.f};
        float bov[5];
        #pragma unroll
        for (int nf = 0; nf < 5; ++nf) bov[nf] = bo[ngrp * 80 + nf * 16 + lrow];
        char* base = (char*)uni;
        const int arow = mgrp * 16 + lrow;
        #pragma unroll
        for (int ks = 0; ks < NP_ / 32; ++ks) {
            if (ks < NP_ / 32 - 1) {
                #pragma unroll
                for (int nf = 0; nf < 5; ++nf)
                    uN[nf] = *(const bf16x8*)(&UB[(size_t)(nf * 16 + lrow) * NP_ + (ks + 1) * 32 + lk]);
            }
            int a = (arow * 1280 + (ks * 32 + lk) * 2) ^ ((arow & 7) << 4);
            bf16x8 af0 = *(const bf16x8*)(base + a);
            __builtin_amdgcn_s_setprio(1);
            #pragma unroll
            for (int nf = 0; nf < 5; ++nf)
                acc2[nf] = __builtin_amdgcn_mfma_f32_16x16x32_bf16(af0, uC[nf], acc2[nf], 0, 0, 0);
            __builtin_amdgcn_s_setprio(0);
            #pragma unroll
            for (int nf = 0; nf < 5; ++nf) uC[nf] = uN[nf];
        }
        float* op = out + ((size_t)b * S_ + s0) * C_;
        #pragma unroll
        for (int r = 0; r < 4; ++r)
            #pragma unroll
            for (int nf = 0; nf < 5; ++nf)
                op[(size_t)(mgrp * 16 + (l >> 4) * 4 + r) * C_ +
                   ngrp * 80 + nf * 16 + lrow] = acc2[nf][r] + bov[nf];
    }
}

// ---------------------------------------------------------------- launch
extern "C" void kernel_launch(void* const* d_in, const int* in_sizes, int n_in,
                              void* d_out, int out_size, void* d_ws, size_t ws_size,
                              hipStream_t stream) {
    const float* hs   = (const float*)d_in[0];
    const float* ehs  = (const float*)d_in[1];
    const float* harm = (const float*)d_in[2];
    const float* Wq   = (const float*)d_in[3];
    const float* Wk   = (const float*)d_in[4];
    const float* Wv   = (const float*)d_in[5];
    const float* Wo   = (const float*)d_in[6];
    const float* bo   = (const float*)d_in[7];
    float* out = (float*)d_out;

    char* ws = (char*)d_ws;
    unsigned short* ehs_bf = (unsigned short*)(ws);             //  1,966,080
    unsigned short* Bmat   = (unsigned short*)(ws + 1966080);   //  7,864,320
    float*          pen    = (float*)        (ws + 9830400);    //      5,120
    unsigned short* Wp     = (unsigned short*)(ws + 9835520);   //  6,553,600
    unsigned short* U      = (unsigned short*)(ws + 16389120);  //  6,553,600
    // total 22,942,720 bytes

    build_M <<<dim3(3, 8, 8),  256, 0, stream>>>(Wq, Wk, Wv, Wo, Bmat);
    prep_ehs<<<dim3(20, 16),   256, 0, stream>>>(ehs, harm, ehs_bf, pen);
    gemm_WpU<<<dim3(640),      512, 0, stream>>>(ehs_bf, Bmat, Wp, U);
    fused_attn<<<dim3(1024),  1024, 0, stream>>>(hs, Wp, U, pen, bo, out);
}

// Round 5
// 331.617 us; speedup vs baseline: 1.2789x; 1.2789x over previous
//
#include <hip/hip_runtime.h>
#include <hip/hip_bf16.h>

#define B_ 16
#define S_ 4096
#define C_ 320
#define KK_ 77
#define D_ 768
#define H_ 8
#define DH_ 40
#define KP_ 80           // padded keys per head
#define NP_ (H_ * KP_)   // 640
#define TAU_ 0.1f
#define GAMMA_ 1.0f
#define EPS_ 1e-12f

typedef __bf16 bf16x8 __attribute__((ext_vector_type(8)));
typedef float f32x4 __attribute__((ext_vector_type(4)));
typedef unsigned short ushort8v __attribute__((ext_vector_type(8)));

__device__ __forceinline__ unsigned short f2bf(float f) {
    union { float f; unsigned u; } v; v.f = f;
    unsigned r = v.u + 0x7fffu + ((v.u >> 16) & 1u);
    return (unsigned short)(r >> 16);
}

// ---------------------------------------------------------------- build_M
// Bmat[n][Dk] bf16, n = which*2560 + h*320 + c:
//   which=0: scale * sum_d Wk[Dk, h*40+d] * Wq[c, h*40+d]
//   which=1:         sum_d Wv[Dk, h*40+d] * Wo[h*40+d, c]
__global__ __launch_bounds__(256) void build_M(const float* __restrict__ Wq,
        const float* __restrict__ Wk, const float* __restrict__ Wv,
        const float* __restrict__ Wo, unsigned short* __restrict__ Bmat) {
    const int Dk = blockIdx.x * 256 + threadIdx.x;     // 0..767
    const int h = blockIdx.y;
    const int which = blockIdx.z >> 2;
    const int c0 = (blockIdx.z & 3) * 80;
    __shared__ float wlds[80 * 44];                    // float4-readable
    for (int i = threadIdx.x; i < 80 * DH_; i += 256) {
        int c = i / DH_, d = i % DH_;
        wlds[c * 44 + d] = which
            ? Wo[(size_t)(h * DH_ + d) * C_ + (c0 + c)]
            : Wq[(size_t)(c0 + c) * C_ + h * DH_ + d];
    }
    float a[DH_];
    const float* Arow = (which ? Wv : Wk) + (size_t)Dk * C_ + h * DH_;
    #pragma unroll
    for (int d = 0; d < DH_; ++d) a[d] = Arow[d];
    __syncthreads();
    const float scale = 0.15811388300841898f;          // 1/sqrt(40)
    for (int c = 0; c < 80; ++c) {
        float s = 0.f;
        #pragma unroll
        for (int q = 0; q < 10; ++q) {
            float4 wv4 = *(const float4*)&wlds[c * 44 + q * 4];
            s += a[q * 4 + 0] * wv4.x + a[q * 4 + 1] * wv4.y
               + a[q * 4 + 2] * wv4.z + a[q * 4 + 3] * wv4.w;
        }
        if (!which) s *= scale;
        int n = which * 2560 + h * C_ + c0 + c;
        Bmat[(size_t)n * D_ + Dk] = f2bf(s);
    }
}

// ---------------------------------------------------------------- prep_ehs
// ehs f32 -> ehs_bf [16][80][768] bf16 (kk>=77 zero), + penalty (padded to 80)
__global__ __launch_bounds__(256) void prep_ehs(const float* __restrict__ ehs,
        const float* __restrict__ harm, unsigned short* __restrict__ ehs_bf,
        float* __restrict__ pen) {
    const int w = threadIdx.x >> 6, l = threadIdx.x & 63;
    const int kk = blockIdx.x * 4 + w, b = blockIdx.y;
    const size_t obase = ((size_t)b * KP_ + kk) * D_;
    if (kk >= KK_) {
        #pragma unroll
        for (int j = 0; j < 12; ++j) ehs_bf[obase + l + j * 64] = 0;
        if (l == 0) pen[b * KP_ + kk] = 0.f;
        return;
    }
    const float* er = ehs + ((size_t)b * KK_ + kk) * D_;
    float ss = 0.f, dd = 0.f, hh = 0.f;
    #pragma unroll
    for (int j = 0; j < 12; ++j) {
        float e = er[l + j * 64], hv = harm[l + j * 64];
        ehs_bf[obase + l + j * 64] = f2bf(e);
        ss += e * e; dd += e * hv; hh += hv * hv;
    }
    #pragma unroll
    for (int off = 32; off; off >>= 1) {
        ss += __shfl_xor(ss, off);
        dd += __shfl_xor(dd, off);
        hh += __shfl_xor(hh, off);
    }
    if (l == 0) {
        float cs = dd / (fmaxf(sqrtf(ss), EPS_) * fmaxf(sqrtf(hh), EPS_));
        pen[b * KP_ + kk] = GAMMA_ * fmaxf(cs - TAU_, 0.f);
    }
}

// ---------------------------------------------------------------- gemm_WpU
// out[kk][n] = ehs_bf[b] @ Bmat^T ; n<2560 -> Wp[b][(h,kk)][c], else U[b][c'][(h,kk)]
// A (ehs_bf[b], 120KB) staged in LDS (XOR-swizzled); B 2-deep pipelined, redundancy 1.
__global__ __launch_bounds__(1024) void gemm_WpU(
        const unsigned short* __restrict__ ehs_bf,
        const unsigned short* __restrict__ Bmat,
        unsigned short* __restrict__ Wp, unsigned short* __restrict__ U) {
    const int id = blockIdx.x;               // 160 = 16 b * 10 nt
    const int b = id & 15, nt = id >> 4;
    const int tid = threadIdx.x, w = tid >> 6, l = tid & 63;
    const int lrow = l & 15, lgrp = l >> 4, lk = lgrp * 8;
    __shared__ unsigned short Al[80 * 768];  // 122880 B, swizzled
    char* lds = (char*)Al;

    // stage A: 7680 16B chunks
    const unsigned short* Ag = ehs_bf + (size_t)b * KP_ * D_;
    #pragma unroll
    for (int it = 0; it < 8; ++it) {
        int ch = tid + it * 1024;
        if (ch < 7680) {
            int byte = ch * 16, row = byte / 1536;
            int a = byte ^ ((row & 7) << 4);
            *(ushort8v*)(lds + a) = *(const ushort8v*)(Ag + ch * 8);
        }
    }
    const int n0 = nt * 512 + w * 32;
    const unsigned short* Br = Bmat + (size_t)(n0 + lrow) * D_ + lk;
    bf16x8 bC[2], bN[2];
    #pragma unroll
    for (int nf = 0; nf < 2; ++nf)
        bC[nf] = *(const bf16x8*)(Br + (size_t)nf * 16 * D_);
    __syncthreads();

    f32x4 acc[5][2];
    #pragma unroll
    for (int mf = 0; mf < 5; ++mf)
        #pragma unroll
        for (int nf = 0; nf < 2; ++nf) acc[mf][nf] = (f32x4){0.f, 0.f, 0.f, 0.f};
    #pragma unroll
    for (int ks = 0; ks < D_ / 32; ++ks) {
        if (ks < D_ / 32 - 1) {
            #pragma unroll
            for (int nf = 0; nf < 2; ++nf)
                bN[nf] = *(const bf16x8*)(Br + (size_t)nf * 16 * D_ + (ks + 1) * 32);
        }
        bf16x8 af[5];
        #pragma unroll
        for (int mf = 0; mf < 5; ++mf) {
            int row = mf * 16 + lrow;
            int a = (row * 1536 + (ks * 32 + lk) * 2) ^ ((row & 7) << 4);
            af[mf] = *(const bf16x8*)(lds + a);
        }
        __builtin_amdgcn_s_setprio(1);
        #pragma unroll
        for (int mf = 0; mf < 5; ++mf)
            #pragma unroll
            for (int nf = 0; nf < 2; ++nf)
                acc[mf][nf] = __builtin_amdgcn_mfma_f32_16x16x32_bf16(
                    af[mf], bC[nf], acc[mf][nf], 0, 0, 0);
        __builtin_amdgcn_s_setprio(0);
        #pragma unroll
        for (int nf = 0; nf < 2; ++nf) bC[nf] = bN[nf];
    }
    #pragma unroll
    for (int nf = 0; nf < 2; ++nf) {
        const int col = n0 + nf * 16 + lrow;
        if (col < 2560) {
            const int h = col / C_, c = col % C_;
            #pragma unroll
            for (int mf = 0; mf < 5; ++mf)
                #pragma unroll
                for (int r = 0; r < 4; ++r) {
                    int kk = mf * 16 + lgrp * 4 + r;
                    Wp[((size_t)b * NP_ + h * KP_ + kk) * C_ + c] = f2bf(acc[mf][nf][r]);
                }
        } else {
            const int n2 = col - 2560;
            const int h = n2 / C_, c = n2 % C_;
            #pragma unroll
            for (int mf = 0; mf < 5; ++mf)
                #pragma unroll
                for (int r = 0; r < 4; ++r) {
                    int kk = mf * 16 + lgrp * 4 + r;
                    U[((size_t)b * C_ + c) * NP_ + h * KP_ + kk] = f2bf(acc[mf][nf][r]);
                }
        }
    }
}

// ---------------------------------------------------------------- fused attn
// 1024 blocks, 512 threads, 64 S-rows per block. Swapped-operand QK^T:
// acc[nf][mf] = D[kk][m] (row=lgrp*4+r -> kk, col=lane&15 -> m).
// LDS union 80KB: hs[64][320] bf16 (XOR swz, stride 640B) then P[64][640] (stride 1280B).
__global__ __launch_bounds__(512, 4) void fused_attn(
        const float* __restrict__ hs, const unsigned short* __restrict__ Wp,
        const unsigned short* __restrict__ U, const float* __restrict__ pen,
        const float* __restrict__ bo, float* __restrict__ out) {
    const int id = blockIdx.x;                  // 1024 = 8 xcd * 128
    const int xcd = id & 7, rest = id >> 3;
    const int b = xcd * 2 + (rest >> 6);        // 2 batches per XCD (L2-resident Wp/U)
    const int s0 = (rest & 63) * 64;
    __shared__ unsigned short uni[40960];       // 81920 B
    char* lds = (char*)uni;
    const int tid = threadIdx.x, w = tid >> 6, l = tid & 63;
    const int lrow = l & 15, lgrp = l >> 4, lk = lgrp * 8;

    // penalty: pv4[nf][r] = pen[b*80 + nf*16 + lgrp*4 + r]
    float4 pv4[5];
    #pragma unroll
    for (int nf = 0; nf < 5; ++nf)
        pv4[nf] = *(const float4*)(pen + b * KP_ + nf * 16 + lgrp * 4);

    // phase-2 role & bias (7 waves x 48 cols, wave 7 idle)
    const int c0 = w * 48;
    float bov[3];
    #pragma unroll
    for (int nf = 0; nf < 3; ++nf)
        bov[nf] = (c0 + nf * 16 < C_) ? bo[c0 + nf * 16 + lrow] : 0.f;

    // prefetch phase-1 Wp frags ks=0 (A-operand: rows = kk of head w)
    const unsigned short* WpB = Wp + ((size_t)b * NP_ + w * KP_) * C_;
    bf16x8 bC[5], bN[5];
    #pragma unroll
    for (int nf = 0; nf < 5; ++nf)
        bC[nf] = *(const bf16x8*)(WpB + (size_t)(nf * 16 + lrow) * C_ + lk);

    // stage hs tile 64x320 f32 -> bf16, swizzled, stride 640B
    const float4* hv = (const float4*)(hs + ((size_t)b * S_ + s0) * C_);
    #pragma unroll
    for (int it = 0; it < 10; ++it) {
        int i = tid + it * 512;
        float4 v = hv[i];
        int r = i / 80, c = (i * 4) % C_;
        ushort4 u;
        u.x = f2bf(v.x); u.y = f2bf(v.y); u.z = f2bf(v.z); u.w = f2bf(v.w);
        int a = (r * 640 + c * 2) ^ ((r & 7) << 4);
        *(ushort4*)(lds + a) = u;
    }
    __syncthreads();

    // ---- phase 1: D[kk][m] = Wp_frag x hs_frag, 2-deep pipelined
    f32x4 acc[5][4];
    #pragma unroll
    for (int nf = 0; nf < 5; ++nf)
        #pragma unroll
        for (int mf = 0; mf < 4; ++mf) acc[nf][mf] = (f32x4){0.f, 0.f, 0.f, 0.f};
    #pragma unroll
    for (int ks = 0; ks < C_ / 32; ++ks) {
        if (ks < C_ / 32 - 1) {
            #pragma unroll
            for (int nf = 0; nf < 5; ++nf)
                bN[nf] = *(const bf16x8*)(WpB + (size_t)(nf * 16 + lrow) * C_ + (ks + 1) * 32 + lk);
        }
        bf16x8 hf_[4];
        #pragma unroll
        for (int mf = 0; mf < 4; ++mf) {
            int row = mf * 16 + lrow;
            int a = (row * 640 + (ks * 32 + lk) * 2) ^ ((row & 7) << 4);
            hf_[mf] = *(const bf16x8*)(lds + a);
        }
        __builtin_amdgcn_s_setprio(1);
        #pragma unroll
        for (int nf = 0; nf < 5; ++nf)
            #pragma unroll
            for (int mf = 0; mf < 4; ++mf)
                acc[nf][mf] = __builtin_amdgcn_mfma_f32_16x16x32_bf16(
                    bC[nf], hf_[mf], acc[nf][mf], 0, 0, 0);
        __builtin_amdgcn_s_setprio(0);
        #pragma unroll
        for (int nf = 0; nf < 5; ++nf) bC[nf] = bN[nf];
    }

    // ---- softmax over kk (in-lane 20 + shfl_xor 16,32), probs left in acc
    float inv4[4];
    #pragma unroll
    for (int mf = 0; mf < 4; ++mf) {
        float mx = -1e30f;
        #pragma unroll
        for (int nf = 0; nf < 5; ++nf)
            #pragma unroll
            for (int r = 0; r < 4; ++r) {
                float x = acc[nf][mf][r] - ((const float*)&pv4[nf])[r];
                if (nf == 4 && r >= 1) x = (lgrp == 3) ? -1e30f : x;   // kk 77..79 mask
                acc[nf][mf][r] = x;
                mx = fmaxf(mx, x);
            }
        mx = fmaxf(mx, __shfl_xor(mx, 16));
        mx = fmaxf(mx, __shfl_xor(mx, 32));
        float s = 0.f;
        #pragma unroll
        for (int nf = 0; nf < 5; ++nf)
            #pragma unroll
            for (int r = 0; r < 4; ++r) {
                float e = __expf(acc[nf][mf][r] - mx);
                acc[nf][mf][r] = e; s += e;
            }
        s += __shfl_xor(s, 16);
        s += __shfl_xor(s, 32);
        inv4[mf] = 1.f / s;
    }
    __syncthreads();   // all waves done reading hs region

    // prefetch U ks=0 (overlaps P ds_writes)
    bf16x8 uC[3], uN[3];
    #pragma unroll
    for (int nf = 0; nf < 3; ++nf)
        if (c0 + nf * 16 < C_)
            uC[nf] = *(const bf16x8*)(U + ((size_t)b * C_ + c0 + nf * 16 + lrow) * NP_ + lk);

    // write P: packed ds_write_b64, addr (m*1280 + (w*80+kk)*2) ^ ((m&7)<<4)
    #pragma unroll
    for (int mf = 0; mf < 4; ++mf) {
        const int m = mf * 16 + lrow;
        const float inv = inv4[mf];
        #pragma unroll
        for (int nf = 0; nf < 5; ++nf) {
            ushort4 u;
            u.x = f2bf(acc[nf][mf][0] * inv);
            u.y = f2bf(acc[nf][mf][1] * inv);
            u.z = f2bf(acc[nf][mf][2] * inv);
            u.w = f2bf(acc[nf][mf][3] * inv);
            int a = (m * 1280 + (w * KP_ + nf * 16 + lgrp * 4) * 2) ^ ((m & 7) << 4);
            *(ushort4*)(lds + a) = u;
        }
    }
    __syncthreads();

    // ---- phase 2: out = P @ U + bo (7 waves x 48 cols, redundancy 1), 2-deep
    {
        f32x4 acc2[4][3];
        #pragma unroll
        for (int mf = 0; mf < 4; ++mf)
            #pragma unroll
            for (int nf = 0; nf < 3; ++nf) acc2[mf][nf] = (f32x4){0.f, 0.f, 0.f, 0.f};
        #pragma unroll
        for (int ks = 0; ks < NP_ / 32; ++ks) {
            if (ks < NP_ / 32 - 1) {
                #pragma unroll
                for (int nf = 0; nf < 3; ++nf)
                    if (c0 + nf * 16 < C_)
                        uN[nf] = *(const bf16x8*)(U + ((size_t)b * C_ + c0 + nf * 16 + lrow) * NP_ + (ks + 1) * 32 + lk);
            }
            bf16x8 pa[4];
            #pragma unroll
            for (int mf = 0; mf < 4; ++mf) {
                int row = mf * 16 + lrow;
                int a = (row * 1280 + (ks * 32 + lk) * 2) ^ ((row & 7) << 4);
                pa[mf] = *(const bf16x8*)(lds + a);
            }
            __builtin_amdgcn_s_setprio(1);
            #pragma unroll
            for (int mf = 0; mf < 4; ++mf)
                #pragma unroll
                for (int nf = 0; nf < 3; ++nf)
                    if (c0 + nf * 16 < C_)
                        acc2[mf][nf] = __builtin_amdgcn_mfma_f32_16x16x32_bf16(
                            pa[mf], uC[nf], acc2[mf][nf], 0, 0, 0);
            __builtin_amdgcn_s_setprio(0);
            #pragma unroll
            for (int nf = 0; nf < 3; ++nf) uC[nf] = uN[nf];
        }
        float* op = out + ((size_t)b * S_ + s0) * C_;
        #pragma unroll
        for (int mf = 0; mf < 4; ++mf)
            #pragma unroll
            for (int r = 0; r < 4; ++r)
                #pragma unroll
                for (int nf = 0; nf < 3; ++nf)
                    if (c0 + nf * 16 < C_)
                        op[(size_t)(mf * 16 + lgrp * 4 + r) * C_ + c0 + nf * 16 + lrow] =
                            acc2[mf][nf][r] + bov[nf];
    }
}

// ---------------------------------------------------------------- launch
extern "C" void kernel_launch(void* const* d_in, const int* in_sizes, int n_in,
                              void* d_out, int out_size, void* d_ws, size_t ws_size,
                              hipStream_t stream) {
    const float* hs   = (const float*)d_in[0];
    const float* ehs  = (const float*)d_in[1];
    const float* harm = (const float*)d_in[2];
    const float* Wq   = (const float*)d_in[3];
    const float* Wk   = (const float*)d_in[4];
    const float* Wv   = (const float*)d_in[5];
    const float* Wo   = (const float*)d_in[6];
    const float* bo   = (const float*)d_in[7];
    float* out = (float*)d_out;

    char* ws = (char*)d_ws;
    unsigned short* ehs_bf = (unsigned short*)(ws);             //  1,966,080
    unsigned short* Bmat   = (unsigned short*)(ws + 1966080);   //  7,864,320
    float*          pen    = (float*)        (ws + 9830400);    //      5,120
    unsigned short* Wp     = (unsigned short*)(ws + 9835520);   //  6,553,600
    unsigned short* U      = (unsigned short*)(ws + 16389120);  //  6,553,600
    // total 22,942,720 bytes (unchanged)

    build_M <<<dim3(3, 8, 8),  256, 0, stream>>>(Wq, Wk, Wv, Wo, Bmat);
    prep_ehs<<<dim3(20, 16),   256, 0, stream>>>(ehs, harm, ehs_bf, pen);
    gemm_WpU<<<dim3(160),     1024, 0, stream>>>(ehs_bf, Bmat, Wp, U);
    fused_attn<<<dim3(1024),   512, 0, stream>>>(hs, Wp, U, pen, bo, out);
}

// Round 7
// 176.310 us; speedup vs baseline: 2.4055x; 1.8809x over previous
//
#include <hip/hip_runtime.h>
#include <hip/hip_bf16.h>

#define B_ 16
#define S_ 4096
#define C_ 320
#define KK_ 77
#define D_ 768
#define H_ 8
#define DH_ 40
#define KP_ 80           // padded keys per head
#define NP_ (H_ * KP_)   // 640
#define TAU_ 0.1f
#define GAMMA_ 1.0f
#define EPS_ 1e-12f

typedef __bf16 bf16x8 __attribute__((ext_vector_type(8)));
typedef float f32x4 __attribute__((ext_vector_type(4)));
typedef unsigned short ushort8v __attribute__((ext_vector_type(8)));
typedef unsigned int u32;

__device__ __forceinline__ unsigned short f2bf(float f) {
    union { float f; unsigned u; } v; v.f = f;
    unsigned r = v.u + 0x7fffu + ((v.u >> 16) & 1u);
    return (unsigned short)(r >> 16);
}

// async 16B-per-lane global->LDS DMA (lds dest = wave-uniform base + lane*16)
__device__ __forceinline__ void gld16(const unsigned short* g, char* l) {
    __builtin_amdgcn_global_load_lds(
        (const __attribute__((address_space(1))) u32*)g,
        (__attribute__((address_space(3))) u32*)l, 16, 0, 0);
}

// ---------------------------------------------------------------- build_M
__global__ __launch_bounds__(256) void build_M(const float* __restrict__ Wq,
        const float* __restrict__ Wk, const float* __restrict__ Wv,
        const float* __restrict__ Wo, unsigned short* __restrict__ Bmat) {
    const int Dk = blockIdx.x * 256 + threadIdx.x;     // 0..767
    const int h = blockIdx.y;
    const int which = blockIdx.z >> 2;
    const int c0 = (blockIdx.z & 3) * 80;
    __shared__ float wlds[80 * 44];
    for (int i = threadIdx.x; i < 80 * DH_; i += 256) {
        int c = i / DH_, d = i % DH_;
        wlds[c * 44 + d] = which
            ? Wo[(size_t)(h * DH_ + d) * C_ + (c0 + c)]
            : Wq[(size_t)(c0 + c) * C_ + h * DH_ + d];
    }
    float a[DH_];
    const float* Arow = (which ? Wv : Wk) + (size_t)Dk * C_ + h * DH_;
    #pragma unroll
    for (int d = 0; d < DH_; ++d) a[d] = Arow[d];
    __syncthreads();
    const float scale = 0.15811388300841898f;          // 1/sqrt(40)
    for (int c = 0; c < 80; ++c) {
        float s = 0.f;
        #pragma unroll
        for (int q = 0; q < 10; ++q) {
            float4 wv4 = *(const float4*)&wlds[c * 44 + q * 4];
            s += a[q * 4 + 0] * wv4.x + a[q * 4 + 1] * wv4.y
               + a[q * 4 + 2] * wv4.z + a[q * 4 + 3] * wv4.w;
        }
        if (!which) s *= scale;
        int n = which * 2560 + h * C_ + c0 + c;
        Bmat[(size_t)n * D_ + Dk] = f2bf(s);
    }
}

// ---------------------------------------------------------------- prep_ehs
__global__ __launch_bounds__(256) void prep_ehs(const float* __restrict__ ehs,
        const float* __restrict__ harm, unsigned short* __restrict__ ehs_bf,
        float* __restrict__ pen) {
    const int w = threadIdx.x >> 6, l = threadIdx.x & 63;
    const int kk = blockIdx.x * 4 + w, b = blockIdx.y;
    const size_t obase = ((size_t)b * KP_ + kk) * D_;
    if (kk >= KK_) {
        #pragma unroll
        for (int j = 0; j < 12; ++j) ehs_bf[obase + l + j * 64] = 0;
        if (l == 0) pen[b * KP_ + kk] = 0.f;
        return;
    }
    const float* er = ehs + ((size_t)b * KK_ + kk) * D_;
    float ss = 0.f, dd = 0.f, hh = 0.f;
    #pragma unroll
    for (int j = 0; j < 12; ++j) {
        float e = er[l + j * 64], hv = harm[l + j * 64];
        ehs_bf[obase + l + j * 64] = f2bf(e);
        ss += e * e; dd += e * hv; hh += hv * hv;
    }
    #pragma unroll
    for (int off = 32; off; off >>= 1) {
        ss += __shfl_xor(ss, off);
        dd += __shfl_xor(dd, off);
        hh += __shfl_xor(hh, off);
    }
    if (l == 0) {
        float cs = dd / (fmaxf(sqrtf(ss), EPS_) * fmaxf(sqrtf(hh), EPS_));
        pen[b * KP_ + kk] = GAMMA_ * fmaxf(cs - TAU_, 0.f);
    }
}

// ---------------------------------------------------------------- gemm_WpU
__global__ __launch_bounds__(1024) void gemm_WpU(
        const unsigned short* __restrict__ ehs_bf,
        const unsigned short* __restrict__ Bmat,
        unsigned short* __restrict__ Wp, unsigned short* __restrict__ U) {
    const int id = blockIdx.x;               // 160 = 16 b * 10 nt
    const int b = id & 15, nt = id >> 4;
    const int tid = threadIdx.x, w = tid >> 6, l = tid & 63;
    const int lrow = l & 15, lgrp = l >> 4, lk = lgrp * 8;
    __shared__ unsigned short Al[80 * 768];  // 122880 B, swizzled
    char* lds = (char*)Al;

    const unsigned short* Ag = ehs_bf + (size_t)b * KP_ * D_;
    #pragma unroll
    for (int it = 0; it < 8; ++it) {
        int ch = tid + it * 1024;
        if (ch < 7680) {
            int byte = ch * 16, row = byte / 1536;
            int a = byte ^ ((row & 7) << 4);
            *(ushort8v*)(lds + a) = *(const ushort8v*)(Ag + ch * 8);
        }
    }
    const int n0 = nt * 512 + w * 32;
    const unsigned short* Br = Bmat + (size_t)(n0 + lrow) * D_ + lk;
    bf16x8 bC[2], bN[2];
    #pragma unroll
    for (int nf = 0; nf < 2; ++nf)
        bC[nf] = *(const bf16x8*)(Br + (size_t)nf * 16 * D_);
    __syncthreads();

    f32x4 acc[5][2];
    #pragma unroll
    for (int mf = 0; mf < 5; ++mf)
        #pragma unroll
        for (int nf = 0; nf < 2; ++nf) acc[mf][nf] = (f32x4){0.f, 0.f, 0.f, 0.f};
    #pragma unroll
    for (int ks = 0; ks < D_ / 32; ++ks) {
        if (ks < D_ / 32 - 1) {
            #pragma unroll
            for (int nf = 0; nf < 2; ++nf)
                bN[nf] = *(const bf16x8*)(Br + (size_t)nf * 16 * D_ + (ks + 1) * 32);
        }
        bf16x8 af[5];
        #pragma unroll
        for (int mf = 0; mf < 5; ++mf) {
            int row = mf * 16 + lrow;
            int a = (row * 1536 + (ks * 32 + lk) * 2) ^ ((row & 7) << 4);
            af[mf] = *(const bf16x8*)(lds + a);
        }
        __builtin_amdgcn_s_setprio(1);
        #pragma unroll
        for (int mf = 0; mf < 5; ++mf)
            #pragma unroll
            for (int nf = 0; nf < 2; ++nf)
                acc[mf][nf] = __builtin_amdgcn_mfma_f32_16x16x32_bf16(
                    af[mf], bC[nf], acc[mf][nf], 0, 0, 0);
        __builtin_amdgcn_s_setprio(0);
        #pragma unroll
        for (int nf = 0; nf < 2; ++nf) bC[nf] = bN[nf];
    }
    #pragma unroll
    for (int nf = 0; nf < 2; ++nf) {
        const int col = n0 + nf * 16 + lrow;
        if (col < 2560) {
            const int h = col / C_, c = col % C_;
            #pragma unroll
            for (int mf = 0; mf < 5; ++mf)
                #pragma unroll
                for (int r = 0; r < 4; ++r) {
                    int kk = mf * 16 + lgrp * 4 + r;
                    Wp[((size_t)b * NP_ + h * KP_ + kk) * C_ + c] = f2bf(acc[mf][nf][r]);
                }
        } else {
            const int n2 = col - 2560;
            const int h = n2 / C_, c = n2 % C_;
            #pragma unroll
            for (int mf = 0; mf < 5; ++mf)
                #pragma unroll
                for (int r = 0; r < 4; ++r) {
                    int kk = mf * 16 + lgrp * 4 + r;
                    U[((size_t)b * C_ + c) * NP_ + h * KP_ + kk] = f2bf(acc[mf][nf][r]);
                }
        }
    }
}

// ---------------------------------------------------------------- fused attn
// 1024 blocks x 1024 threads, 64 S-rows per block, 1 block/CU (LDS 120KB).
// Phase 1: Wp[b] streamed in 10 x 40KB K-slices via global_load_lds dbuf;
//          16 waves = 2 per head (mh-split). acc[5][2] swapped layout D[kk][m].
// Phase 2: U[b] streamed in 20 x 20KB n-slices via global_load_lds dbuf;
//          waves 4m x 4n. P in LDS (overlays Wp bufs), hs region reused for U.
__global__ __launch_bounds__(1024) void fused_attn(
        const float* __restrict__ hs, const unsigned short* __restrict__ Wp,
        const unsigned short* __restrict__ U, const float* __restrict__ pen,
        const float* __restrict__ bo, float* __restrict__ out) {
    const int id = blockIdx.x;                  // 1024 = 8 xcd * 128
    const int xcd = id & 7, rest = id >> 3;
    const int b = xcd * 2 + (rest >> 6);        // 2 batches per XCD
    const int s0 = (rest & 63) * 64;
    __shared__ __align__(16) char smem[122880];
    char* HS = smem;                            // 40960: hs tile [64][320] bf16 swz
    char* WB0 = smem + 40960;                   // Wp slice dbuf 2x40960
    char* WB1 = smem + 81920;
    char* PB  = smem + 40960;                   // P [64][640] bf16 (overlays WB)
    char* UB0 = smem;                           // U slice dbuf 2x20480 (overlays HS)
    char* UB1 = smem + 20480;
    const int tid = threadIdx.x, w = tid >> 6, l = tid & 63;
    const int lrow = l & 15, lgrp = l >> 4, lk = lgrp * 8;
    const int h = w & 7, mh = w >> 3;           // phase-1 roles
    const int mgrp = w & 3, ngrp = w >> 2;      // phase-2 roles

    const unsigned short* Wpb = Wp + (size_t)b * NP_ * C_;
    const unsigned short* Ub  = U  + (size_t)b * C_ * NP_;

    // ---- stage Wp K-slice ks into buf: LDS tile [n 640][4 chunks of 16B],
    //      chunk swizzle c ^ ((n>>1)&3), inverse applied on global source.
    auto stage_wp = [&](int ks, char* buf) {
        #pragma unroll
        for (int j = 0; j < 2; ++j) {
            int L = w * 128 + j * 64 + l;       // chunk id 0..2047
            int n = L >> 2, cs = (L & 3) ^ ((n >> 1) & 3);
            gld16(Wpb + (size_t)n * C_ + ks * 32 + cs * 8,
                  buf + (w * 128 + j * 64) * 16);
        }
        if (w < 8) {
            int L = 2048 + w * 64 + l;          // chunks 2048..2559
            int n = L >> 2, cs = (L & 3) ^ ((n >> 1) & 3);
            gld16(Wpb + (size_t)n * C_ + ks * 32 + cs * 8,
                  buf + (2048 + w * 64) * 16);
        }
    };
    // ---- stage U n-slice ksn into buf: LDS tile [c 320][4 chunks], same swz.
    auto stage_u = [&](int ksn, char* buf) {
        {
            int L = w * 64 + l;                 // 0..1023
            int c = L >> 2, cs = (L & 3) ^ ((c >> 1) & 3);
            gld16(Ub + (size_t)c * NP_ + ksn * 32 + cs * 8, buf + (w * 64) * 16);
        }
        if (w < 4) {
            int L = 1024 + w * 64 + l;          // 1024..1279
            int c = L >> 2, cs = (L & 3) ^ ((c >> 1) & 3);
            gld16(Ub + (size_t)c * NP_ + ksn * 32 + cs * 8,
                  buf + (1024 + w * 64) * 16);
        }
    };

    // prologue: issue Wp slice 0 DMA, reg-stage hs tile (f32->bf16, R4 swizzle)
    stage_wp(0, WB0);
    const float4* hv = (const float4*)(hs + ((size_t)b * S_ + s0) * C_);
    #pragma unroll
    for (int it = 0; it < 5; ++it) {            // 5 x 1024 = 5120 float4 = 64x320 f32
        int i = tid + it * 1024;
        float4 v = hv[i];
        int r = i / 80, c = (i * 4) % C_;
        ushort4 u;
        u.x = f2bf(v.x); u.y = f2bf(v.y); u.z = f2bf(v.z); u.w = f2bf(v.w);
        int a = (r * 640 + c * 2) ^ ((r & 7) << 4);
        *(ushort4*)(HS + a) = u;
    }
    float4 pv4[5];
    #pragma unroll
    for (int nf = 0; nf < 5; ++nf)
        pv4[nf] = *(const float4*)(pen + b * KP_ + nf * 16 + lgrp * 4);
    __syncthreads();   // drains DMA (vmcnt) + ds_writes

    // ---- phase 1: D[kk][m] over 10 K-slices, LDS double-buffered
    f32x4 acc[5][2];
    #pragma unroll
    for (int nf = 0; nf < 5; ++nf)
        #pragma unroll
        for (int mf = 0; mf < 2; ++mf) acc[nf][mf] = (f32x4){0.f, 0.f, 0.f, 0.f};
    for (int ks = 0; ks < 10; ++ks) {
        if (ks < 9) stage_wp(ks + 1, (ks & 1) ? WB0 : WB1);
        char* wb = (ks & 1) ? WB1 : WB0;
        bf16x8 bC[5], hf[2];
        #pragma unroll
        for (int nf = 0; nf < 5; ++nf) {
            int n = h * KP_ + nf * 16 + lrow;
            bC[nf] = *(const bf16x8*)(wb + n * 64 + ((lgrp ^ ((n >> 1) & 3)) << 4));
        }
        #pragma unroll
        for (int mf = 0; mf < 2; ++mf) {
            int row = mh * 32 + mf * 16 + lrow;
            int a = (row * 640 + (ks * 32 + lk) * 2) ^ ((row & 7) << 4);
            hf[mf] = *(const bf16x8*)(HS + a);
        }
        __builtin_amdgcn_s_setprio(1);
        #pragma unroll
        for (int nf = 0; nf < 5; ++nf)
            #pragma unroll
            for (int mf = 0; mf < 2; ++mf)
                acc[nf][mf] = __builtin_amdgcn_mfma_f32_16x16x32_bf16(
                    bC[nf], hf[mf], acc[nf][mf], 0, 0, 0);
        __builtin_amdgcn_s_setprio(0);
        __syncthreads();   // all reads of this slice done; DMA for next landed
    }

    // issue U slice 0 DMA now (lands under softmax; HS region is dead)
    stage_u(0, UB0);

    // ---- softmax over kk (in-lane + shfl 16,32); probs stay in acc
    float inv2[2];
    #pragma unroll
    for (int mf = 0; mf < 2; ++mf) {
        float mx = -1e30f;
        #pragma unroll
        for (int nf = 0; nf < 5; ++nf)
            #pragma unroll
            for (int r = 0; r < 4; ++r) {
                float x = acc[nf][mf][r] - ((const float*)&pv4[nf])[r];
                if (nf == 4 && r >= 1) x = (lgrp == 3) ? -1e30f : x;  // kk 77..79
                acc[nf][mf][r] = x;
                mx = fmaxf(mx, x);
            }
        mx = fmaxf(mx, __shfl_xor(mx, 16));
        mx = fmaxf(mx, __shfl_xor(mx, 32));
        float s = 0.f;
        #pragma unroll
        for (int nf = 0; nf < 5; ++nf)
            #pragma unroll
            for (int r = 0; r < 4; ++r) {
                float e = __expf(acc[nf][mf][r] - mx);
                acc[nf][mf][r] = e; s += e;
            }
        s += __shfl_xor(s, 16);
        s += __shfl_xor(s, 32);
        inv2[mf] = 1.f / s;
    }

    // write P (bf16) into PB: addr rel = (m*1280 + col*2) ^ ((m&7)<<4)
    #pragma unroll
    for (int mf = 0; mf < 2; ++mf) {
        const int m = mh * 32 + mf * 16 + lrow;
        const float inv = inv2[mf];
        #pragma unroll
        for (int nf = 0; nf < 5; ++nf) {
            ushort4 u;
            u.x = f2bf(acc[nf][mf][0] * inv);
            u.y = f2bf(acc[nf][mf][1] * inv);
            u.z = f2bf(acc[nf][mf][2] * inv);
            u.w = f2bf(acc[nf][mf][3] * inv);
            int a = (m * 1280 + (h * KP_ + nf * 16 + lgrp * 4) * 2) ^ ((m & 7) << 4);
            *(ushort4*)(PB + a) = u;
        }
    }
    __syncthreads();   // P visible, U slice 0 landed

    // ---- phase 2: out = P @ U + bo over 20 n-slices, LDS double-buffered
    f32x4 acc2[5];
    #pragma unroll
    for (int nf = 0; nf < 5; ++nf) acc2[nf] = (f32x4){0.f, 0.f, 0.f, 0.f};
    float bov[5];
    #pragma unroll
    for (int nf = 0; nf < 5; ++nf) bov[nf] = bo[ngrp * KP_ + nf * 16 + lrow];
    for (int ksn = 0; ksn < 20; ++ksn) {
        if (ksn < 19) stage_u(ksn + 1, (ksn & 1) ? UB0 : UB1);
        char* ub = (ksn & 1) ? UB1 : UB0;
        bf16x8 pa, uf[5];
        {
            int row = mgrp * 16 + lrow;
            int a = (row * 1280 + (ksn * 32 + lk) * 2) ^ ((row & 7) << 4);
            pa = *(const bf16x8*)(PB + a);
        }
        #pragma unroll
        for (int nf = 0; nf < 5; ++nf) {
            int c = ngrp * KP_ + nf * 16 + lrow;
            uf[nf] = *(const bf16x8*)(ub + c * 64 + ((lgrp ^ ((c >> 1) & 3)) << 4));
        }
        __builtin_amdgcn_s_setprio(1);
        #pragma unroll
        for (int nf = 0; nf < 5; ++nf)
            acc2[nf] = __builtin_amdgcn_mfma_f32_16x16x32_bf16(pa, uf[nf], acc2[nf], 0, 0, 0);
        __builtin_amdgcn_s_setprio(0);
        __syncthreads();
    }
    float* op = out + ((size_t)b * S_ + s0) * C_;
    #pragma unroll
    for (int r = 0; r < 4; ++r)
        #pragma unroll
        for (int nf = 0; nf < 5; ++nf)
            op[(size_t)(mgrp * 16 + lgrp * 4 + r) * C_ +
               ngrp * KP_ + nf * 16 + lrow] = acc2[nf][r] + bov[nf];
}

// ---------------------------------------------------------------- launch
extern "C" void kernel_launch(void* const* d_in, const int* in_sizes, int n_in,
                              void* d_out, int out_size, void* d_ws, size_t ws_size,
                              hipStream_t stream) {
    const float* hs   = (const float*)d_in[0];
    const float* ehs  = (const float*)d_in[1];
    const float* harm = (const float*)d_in[2];
    const float* Wq   = (const float*)d_in[3];
    const float* Wk   = (const float*)d_in[4];
    const float* Wv   = (const float*)d_in[5];
    const float* Wo   = (const float*)d_in[6];
    const float* bo   = (const float*)d_in[7];
    float* out = (float*)d_out;

    char* ws = (char*)d_ws;
    unsigned short* ehs_bf = (unsigned short*)(ws);             //  1,966,080
    unsigned short* Bmat   = (unsigned short*)(ws + 1966080);   //  7,864,320
    float*          pen    = (float*)        (ws + 9830400);    //      5,120
    unsigned short* Wp     = (unsigned short*)(ws + 9835520);   //  6,553,600
    unsigned short* U      = (unsigned short*)(ws + 16389120);  //  6,553,600

    build_M <<<dim3(3, 8, 8),  256, 0, stream>>>(Wq, Wk, Wv, Wo, Bmat);
    prep_ehs<<<dim3(20, 16),   256, 0, stream>>>(ehs, harm, ehs_bf, pen);
    gemm_WpU<<<dim3(160),     1024, 0, stream>>>(ehs_bf, Bmat, Wp, U);
    fused_attn<<<dim3(1024),  1024, 0, stream>>>(hs, Wp, U, pen, bo, out);
}

// Round 8
// 175.375 us; speedup vs baseline: 2.4183x; 1.0053x over previous
//
#include <hip/hip_runtime.h>
#include <hip/hip_bf16.h>

#define B_ 16
#define S_ 4096
#define C_ 320
#define KK_ 77
#define D_ 768
#define H_ 8
#define DH_ 40
#define KP_ 80           // padded keys per head
#define NP_ (H_ * KP_)   // 640
#define TAU_ 0.1f
#define GAMMA_ 1.0f
#define EPS_ 1e-12f

typedef __bf16 bf16x8 __attribute__((ext_vector_type(8)));
typedef float f32x4 __attribute__((ext_vector_type(4)));
typedef unsigned short ushort8v __attribute__((ext_vector_type(8)));
typedef unsigned int u32;

#define WAITV(N)  asm volatile("s_waitcnt vmcnt(" #N ")" ::: "memory")
#define WAITVL(N) asm volatile("s_waitcnt vmcnt(" #N ") lgkmcnt(0)" ::: "memory")
#define WAITLG()  asm volatile("s_waitcnt lgkmcnt(0)" ::: "memory")
#define BAR()     __builtin_amdgcn_s_barrier()

__device__ __forceinline__ unsigned short f2bf(float f) {
    union { float f; unsigned u; } v; v.f = f;
    unsigned r = v.u + 0x7fffu + ((v.u >> 16) & 1u);
    return (unsigned short)(r >> 16);
}

// async 16B-per-lane global->LDS DMA (lds dest = wave-uniform base + lane*16)
__device__ __forceinline__ void gld16(const unsigned short* g, char* l) {
    __builtin_amdgcn_global_load_lds(
        (const __attribute__((address_space(1))) u32*)g,
        (__attribute__((address_space(3))) u32*)l, 16, 0, 0);
}

// ---------------------------------------------------------------- build_M
__global__ __launch_bounds__(256) void build_M(const float* __restrict__ Wq,
        const float* __restrict__ Wk, const float* __restrict__ Wv,
        const float* __restrict__ Wo, unsigned short* __restrict__ Bmat) {
    const int Dk = blockIdx.x * 256 + threadIdx.x;     // 0..767
    const int h = blockIdx.y;
    const int which = blockIdx.z >> 2;
    const int c0 = (blockIdx.z & 3) * 80;
    __shared__ float wlds[80 * 44];
    for (int i = threadIdx.x; i < 80 * DH_; i += 256) {
        int c = i / DH_, d = i % DH_;
        wlds[c * 44 + d] = which
            ? Wo[(size_t)(h * DH_ + d) * C_ + (c0 + c)]
            : Wq[(size_t)(c0 + c) * C_ + h * DH_ + d];
    }
    float a[DH_];
    const float* Arow = (which ? Wv : Wk) + (size_t)Dk * C_ + h * DH_;
    #pragma unroll
    for (int d = 0; d < DH_; ++d) a[d] = Arow[d];
    __syncthreads();
    const float scale = 0.15811388300841898f;          // 1/sqrt(40)
    for (int c = 0; c < 80; ++c) {
        float s = 0.f;
        #pragma unroll
        for (int q = 0; q < 10; ++q) {
            float4 wv4 = *(const float4*)&wlds[c * 44 + q * 4];
            s += a[q * 4 + 0] * wv4.x + a[q * 4 + 1] * wv4.y
               + a[q * 4 + 2] * wv4.z + a[q * 4 + 3] * wv4.w;
        }
        if (!which) s *= scale;
        int n = which * 2560 + h * C_ + c0 + c;
        Bmat[(size_t)n * D_ + Dk] = f2bf(s);
    }
}

// ---------------------------------------------------------------- prep_ehs
__global__ __launch_bounds__(256) void prep_ehs(const float* __restrict__ ehs,
        const float* __restrict__ harm, unsigned short* __restrict__ ehs_bf,
        float* __restrict__ pen) {
    const int w = threadIdx.x >> 6, l = threadIdx.x & 63;
    const int kk = blockIdx.x * 4 + w, b = blockIdx.y;
    const size_t obase = ((size_t)b * KP_ + kk) * D_;
    if (kk >= KK_) {
        #pragma unroll
        for (int j = 0; j < 12; ++j) ehs_bf[obase + l + j * 64] = 0;
        if (l == 0) pen[b * KP_ + kk] = 0.f;
        return;
    }
    const float* er = ehs + ((size_t)b * KK_ + kk) * D_;
    float ss = 0.f, dd = 0.f, hh = 0.f;
    #pragma unroll
    for (int j = 0; j < 12; ++j) {
        float e = er[l + j * 64], hv = harm[l + j * 64];
        ehs_bf[obase + l + j * 64] = f2bf(e);
        ss += e * e; dd += e * hv; hh += hv * hv;
    }
    #pragma unroll
    for (int off = 32; off; off >>= 1) {
        ss += __shfl_xor(ss, off);
        dd += __shfl_xor(dd, off);
        hh += __shfl_xor(hh, off);
    }
    if (l == 0) {
        float cs = dd / (fmaxf(sqrtf(ss), EPS_) * fmaxf(sqrtf(hh), EPS_));
        pen[b * KP_ + kk] = GAMMA_ * fmaxf(cs - TAU_, 0.f);
    }
}

// ---------------------------------------------------------------- gemm_WpU
__global__ __launch_bounds__(1024) void gemm_WpU(
        const unsigned short* __restrict__ ehs_bf,
        const unsigned short* __restrict__ Bmat,
        unsigned short* __restrict__ Wp, unsigned short* __restrict__ U) {
    const int id = blockIdx.x;               // 160 = 16 b * 10 nt
    const int b = id & 15, nt = id >> 4;
    const int tid = threadIdx.x, w = tid >> 6, l = tid & 63;
    const int lrow = l & 15, lgrp = l >> 4, lk = lgrp * 8;
    __shared__ unsigned short Al[80 * 768];  // 122880 B, swizzled
    char* lds = (char*)Al;

    const unsigned short* Ag = ehs_bf + (size_t)b * KP_ * D_;
    #pragma unroll
    for (int it = 0; it < 8; ++it) {
        int ch = tid + it * 1024;
        if (ch < 7680) {
            int byte = ch * 16, row = byte / 1536;
            int a = byte ^ ((row & 7) << 4);
            *(ushort8v*)(lds + a) = *(const ushort8v*)(Ag + ch * 8);
        }
    }
    const int n0 = nt * 512 + w * 32;
    const unsigned short* Br = Bmat + (size_t)(n0 + lrow) * D_ + lk;
    bf16x8 bC[2], bN[2];
    #pragma unroll
    for (int nf = 0; nf < 2; ++nf)
        bC[nf] = *(const bf16x8*)(Br + (size_t)nf * 16 * D_);
    __syncthreads();

    f32x4 acc[5][2];
    #pragma unroll
    for (int mf = 0; mf < 5; ++mf)
        #pragma unroll
        for (int nf = 0; nf < 2; ++nf) acc[mf][nf] = (f32x4){0.f, 0.f, 0.f, 0.f};
    #pragma unroll
    for (int ks = 0; ks < D_ / 32; ++ks) {
        if (ks < D_ / 32 - 1) {
            #pragma unroll
            for (int nf = 0; nf < 2; ++nf)
                bN[nf] = *(const bf16x8*)(Br + (size_t)nf * 16 * D_ + (ks + 1) * 32);
        }
        bf16x8 af[5];
        #pragma unroll
        for (int mf = 0; mf < 5; ++mf) {
            int row = mf * 16 + lrow;
            int a = (row * 1536 + (ks * 32 + lk) * 2) ^ ((row & 7) << 4);
            af[mf] = *(const bf16x8*)(lds + a);
        }
        __builtin_amdgcn_s_setprio(1);
        #pragma unroll
        for (int mf = 0; mf < 5; ++mf)
            #pragma unroll
            for (int nf = 0; nf < 2; ++nf)
                acc[mf][nf] = __builtin_amdgcn_mfma_f32_16x16x32_bf16(
                    af[mf], bC[nf], acc[mf][nf], 0, 0, 0);
        __builtin_amdgcn_s_setprio(0);
        #pragma unroll
        for (int nf = 0; nf < 2; ++nf) bC[nf] = bN[nf];
    }
    #pragma unroll
    for (int nf = 0; nf < 2; ++nf) {
        const int col = n0 + nf * 16 + lrow;
        if (col < 2560) {
            const int h = col / C_, c = col % C_;
            #pragma unroll
            for (int mf = 0; mf < 5; ++mf)
                #pragma unroll
                for (int r = 0; r < 4; ++r) {
                    int kk = mf * 16 + lgrp * 4 + r;
                    Wp[((size_t)b * NP_ + h * KP_ + kk) * C_ + c] = f2bf(acc[mf][nf][r]);
                }
        } else {
            const int n2 = col - 2560;
            const int h = n2 / C_, c = n2 % C_;
            #pragma unroll
            for (int mf = 0; mf < 5; ++mf)
                #pragma unroll
                for (int r = 0; r < 4; ++r) {
                    int kk = mf * 16 + lgrp * 4 + r;
                    U[((size_t)b * C_ + c) * NP_ + h * KP_ + kk] = f2bf(acc[mf][nf][r]);
                }
        }
    }
}

// ---------------------------------------------------------------- fused attn
// R6 structure + T4 counted-vmcnt pipeline: raw s_barrier pairs, never drain
// the in-flight next-slice DMA. Slice k+1 lands under slice k's compute.
__global__ __launch_bounds__(1024) void fused_attn(
        const float* __restrict__ hs, const unsigned short* __restrict__ Wp,
        const unsigned short* __restrict__ U, const float* __restrict__ pen,
        const float* __restrict__ bo, float* __restrict__ out) {
    const int id = blockIdx.x;                  // 1024 = 8 xcd * 128
    const int xcd = id & 7, rest = id >> 3;
    const int b = xcd * 2 + (rest >> 6);        // 2 batches per XCD
    const int s0 = (rest & 63) * 64;
    __shared__ __align__(16) char smem[122880];
    char* HS = smem;                            // 40960: hs tile [64][320] bf16 swz
    char* WB0 = smem + 40960;                   // Wp slice dbuf 2x40960
    char* WB1 = smem + 81920;
    char* PB  = smem + 40960;                   // P [64][640] bf16 (overlays WB)
    char* UB0 = smem;                           // U slice dbuf 2x20480 (overlays HS)
    char* UB1 = smem + 20480;
    const int tid = threadIdx.x, w = tid >> 6, l = tid & 63;
    const int lrow = l & 15, lgrp = l >> 4, lk = lgrp * 8;
    const int h = w & 7, mh = w >> 3;           // phase-1 roles
    const int mgrp = w & 3, ngrp = w >> 2;      // phase-2 roles

    const unsigned short* Wpb = Wp + (size_t)b * NP_ * C_;
    const unsigned short* Ub  = U  + (size_t)b * C_ * NP_;

    // stage Wp K-slice: [n 640][4 chunks of 16B], chunk swz c^((n>>1)&3).
    // per-wave DMA insts: 3 (w<8) / 2 (w>=8)
    auto stage_wp = [&](int ks, char* buf) {
        #pragma unroll
        for (int j = 0; j < 2; ++j) {
            int L = w * 128 + j * 64 + l;       // chunk id 0..2047
            int n = L >> 2, cs = (L & 3) ^ ((n >> 1) & 3);
            gld16(Wpb + (size_t)n * C_ + ks * 32 + cs * 8,
                  buf + (w * 128 + j * 64) * 16);
        }
        if (w < 8) {
            int L = 2048 + w * 64 + l;          // chunks 2048..2559
            int n = L >> 2, cs = (L & 3) ^ ((n >> 1) & 3);
            gld16(Wpb + (size_t)n * C_ + ks * 32 + cs * 8,
                  buf + (2048 + w * 64) * 16);
        }
    };
    // stage U n-slice: [c 320][4 chunks]; per-wave insts: 2 (w<4) / 1
    auto stage_u = [&](int ksn, char* buf) {
        {
            int L = w * 64 + l;                 // 0..1023
            int c = L >> 2, cs = (L & 3) ^ ((c >> 1) & 3);
            gld16(Ub + (size_t)c * NP_ + ksn * 32 + cs * 8, buf + (w * 64) * 16);
        }
        if (w < 4) {
            int L = 1024 + w * 64 + l;          // 1024..1279
            int c = L >> 2, cs = (L & 3) ^ ((c >> 1) & 3);
            gld16(Ub + (size_t)c * NP_ + ksn * 32 + cs * 8,
                  buf + (1024 + w * 64) * 16);
        }
    };

    // ---- prologue: pen loads, hs staging, then DMA slices 0+1
    float4 pv4[5];
    #pragma unroll
    for (int nf = 0; nf < 5; ++nf)
        pv4[nf] = *(const float4*)(pen + b * KP_ + nf * 16 + lgrp * 4);
    const float4* hv = (const float4*)(hs + ((size_t)b * S_ + s0) * C_);
    #pragma unroll
    for (int it = 0; it < 5; ++it) {            // 5 x 1024 = 5120 float4 = 64x320 f32
        int i = tid + it * 1024;
        float4 v = hv[i];
        int r = i / 80, c = (i * 4) % C_;
        ushort4 u;
        u.x = f2bf(v.x); u.y = f2bf(v.y); u.z = f2bf(v.z); u.w = f2bf(v.w);
        int a = (r * 640 + c * 2) ^ ((r & 7) << 4);
        *(ushort4*)(HS + a) = u;
    }
    // force pen loads retired so vmcnt below counts DMAs only
    #pragma unroll
    for (int nf = 0; nf < 5; ++nf)
        asm volatile("" :: "v"(pv4[nf].x), "v"(pv4[nf].y),
                           "v"(pv4[nf].z), "v"(pv4[nf].w));
    stage_wp(0, WB0);
    stage_wp(1, WB1);
    if (w < 8) { WAITVL(3); } else { WAITVL(2); }   // slice0 landed, hs ds_writes done
    BAR();

    // ---- phase 1: D[kk][m] over 10 K-slices, counted-vmcnt dbuf
    f32x4 acc[5][2];
    #pragma unroll
    for (int nf = 0; nf < 5; ++nf)
        #pragma unroll
        for (int mf = 0; mf < 2; ++mf) acc[nf][mf] = (f32x4){0.f, 0.f, 0.f, 0.f};
    #pragma unroll
    for (int ks = 0; ks < 10; ++ks) {
        char* wb = (ks & 1) ? WB1 : WB0;
        bf16x8 bC[5], hf[2];
        #pragma unroll
        for (int nf = 0; nf < 5; ++nf) {
            int n = h * KP_ + nf * 16 + lrow;
            bC[nf] = *(const bf16x8*)(wb + n * 64 + ((lgrp ^ ((n >> 1) & 3)) << 4));
        }
        #pragma unroll
        for (int mf = 0; mf < 2; ++mf) {
            int row = mh * 32 + mf * 16 + lrow;
            int a = (row * 640 + (ks * 32 + lk) * 2) ^ ((row & 7) << 4);
            hf[mf] = *(const bf16x8*)(HS + a);
        }
        __builtin_amdgcn_s_setprio(1);
        #pragma unroll
        for (int nf = 0; nf < 5; ++nf)
            #pragma unroll
            for (int mf = 0; mf < 2; ++mf)
                acc[nf][mf] = __builtin_amdgcn_mfma_f32_16x16x32_bf16(
                    bC[nf], hf[mf], acc[nf][mf], 0, 0, 0);
        __builtin_amdgcn_s_setprio(0);
        WAITLG();
        BAR();                              // all waves done reading wb (+ HS at ks=9)
        if (ks < 9) {
            if (ks < 8) {
                stage_wp(ks + 2, wb);       // refill just-read buffer
                if (w < 8) { WAITV(3); } else { WAITV(2); }   // slice ks+1 landed
            } else {
                WAITV(0);                   // slice 9 landed (no new stage)
            }
            BAR();
        }
    }

    // issue U slices 0+1 (HS region dead after exit barrier); land under softmax
    stage_u(0, UB0);
    stage_u(1, UB1);

    // ---- softmax over kk (in-lane + shfl 16,32); probs stay in acc
    float inv2[2];
    #pragma unroll
    for (int mf = 0; mf < 2; ++mf) {
        float mx = -1e30f;
        #pragma unroll
        for (int nf = 0; nf < 5; ++nf)
            #pragma unroll
            for (int r = 0; r < 4; ++r) {
                float x = acc[nf][mf][r] - ((const float*)&pv4[nf])[r];
                if (nf == 4 && r >= 1) x = (lgrp == 3) ? -1e30f : x;  // kk 77..79
                acc[nf][mf][r] = x;
                mx = fmaxf(mx, x);
            }
        mx = fmaxf(mx, __shfl_xor(mx, 16));
        mx = fmaxf(mx, __shfl_xor(mx, 32));
        float s = 0.f;
        #pragma unroll
        for (int nf = 0; nf < 5; ++nf)
            #pragma unroll
            for (int r = 0; r < 4; ++r) {
                float e = __expf(acc[nf][mf][r] - mx);
                acc[nf][mf][r] = e; s += e;
            }
        s += __shfl_xor(s, 16);
        s += __shfl_xor(s, 32);
        inv2[mf] = 1.f / s;
    }

    // write P (bf16) into PB: addr rel = (m*1280 + col*2) ^ ((m&7)<<4)
    #pragma unroll
    for (int mf = 0; mf < 2; ++mf) {
        const int m = mh * 32 + mf * 16 + lrow;
        const float inv = inv2[mf];
        #pragma unroll
        for (int nf = 0; nf < 5; ++nf) {
            ushort4 u;
            u.x = f2bf(acc[nf][mf][0] * inv);
            u.y = f2bf(acc[nf][mf][1] * inv);
            u.z = f2bf(acc[nf][mf][2] * inv);
            u.w = f2bf(acc[nf][mf][3] * inv);
            int a = (m * 1280 + (h * KP_ + nf * 16 + lgrp * 4) * 2) ^ ((m & 7) << 4);
            *(ushort4*)(PB + a) = u;
        }
    }
    if (w < 4) { WAITVL(2); } else { WAITVL(1); }   // U slice0 landed, P writes done
    BAR();

    // ---- phase 2: out = P @ U + bo over 20 n-slices, counted-vmcnt dbuf
    f32x4 acc2[5];
    #pragma unroll
    for (int nf = 0; nf < 5; ++nf) acc2[nf] = (f32x4){0.f, 0.f, 0.f, 0.f};
    #pragma unroll
    for (int ksn = 0; ksn < 20; ++ksn) {
        char* ub = (ksn & 1) ? UB1 : UB0;
        bf16x8 pa, uf[5];
        {
            int row = mgrp * 16 + lrow;
            int a = (row * 1280 + (ksn * 32 + lk) * 2) ^ ((row & 7) << 4);
            pa = *(const bf16x8*)(PB + a);
        }
        #pragma unroll
        for (int nf = 0; nf < 5; ++nf) {
            int c = ngrp * KP_ + nf * 16 + lrow;
            uf[nf] = *(const bf16x8*)(ub + c * 64 + ((lgrp ^ ((c >> 1) & 3)) << 4));
        }
        __builtin_amdgcn_s_setprio(1);
        #pragma unroll
        for (int nf = 0; nf < 5; ++nf)
            acc2[nf] = __builtin_amdgcn_mfma_f32_16x16x32_bf16(pa, uf[nf], acc2[nf], 0, 0, 0);
        __builtin_amdgcn_s_setprio(0);
        WAITLG();
        BAR();                              // all waves done reading ub
        if (ksn < 19) {
            if (ksn < 18) {
                stage_u(ksn + 2, ub);
                if (w < 4) { WAITV(2); } else { WAITV(1); }   // slice ksn+1 landed
            } else {
                WAITV(0);
            }
            BAR();
        }
    }
    float bov[5];
    #pragma unroll
    for (int nf = 0; nf < 5; ++nf) bov[nf] = bo[ngrp * KP_ + nf * 16 + lrow];
    float* op = out + ((size_t)b * S_ + s0) * C_;
    #pragma unroll
    for (int r = 0; r < 4; ++r)
        #pragma unroll
        for (int nf = 0; nf < 5; ++nf)
            op[(size_t)(mgrp * 16 + lgrp * 4 + r) * C_ +
               ngrp * KP_ + nf * 16 + lrow] = acc2[nf][r] + bov[nf];
}

// ---------------------------------------------------------------- launch
extern "C" void kernel_launch(void* const* d_in, const int* in_sizes, int n_in,
                              void* d_out, int out_size, void* d_ws, size_t ws_size,
                              hipStream_t stream) {
    const float* hs   = (const float*)d_in[0];
    const float* ehs  = (const float*)d_in[1];
    const float* harm = (const float*)d_in[2];
    const float* Wq   = (const float*)d_in[3];
    const float* Wk   = (const float*)d_in[4];
    const float* Wv   = (const float*)d_in[5];
    const float* Wo   = (const float*)d_in[6];
    const float* bo   = (const float*)d_in[7];
    float* out = (float*)d_out;

    char* ws = (char*)d_ws;
    unsigned short* ehs_bf = (unsigned short*)(ws);             //  1,966,080
    unsigned short* Bmat   = (unsigned short*)(ws + 1966080);   //  7,864,320
    float*          pen    = (float*)        (ws + 9830400);    //      5,120
    unsigned short* Wp     = (unsigned short*)(ws + 9835520);   //  6,553,600
    unsigned short* U      = (unsigned short*)(ws + 16389120);  //  6,553,600

    build_M <<<dim3(3, 8, 8),  256, 0, stream>>>(Wq, Wk, Wv, Wo, Bmat);
    prep_ehs<<<dim3(20, 16),   256, 0, stream>>>(ehs, harm, ehs_bf, pen);
    gemm_WpU<<<dim3(160),     1024, 0, stream>>>(ehs_bf, Bmat, Wp, U);
    fused_attn<<<dim3(1024),  1024, 0, stream>>>(hs, Wp, U, pen, bo, out);
}